// Round 1
// baseline (134.295 us; speedup 1.0000x reference)
//
#include <hip/hip_runtime.h>
#include <cstddef>

// Problem constants (from reference): BS=16, Q=900, NC=91, M=1600
#define NROWS 14400   // BS*Q
#define NCLS  91
#define MTGT  1600
#define RPB   8       // rows (pred queries) per block -> amortize target re-reads
#define TPB   320     // 5 waves; 1600 = 320*5 exact -> no tail imbalance

__global__ __launch_bounds__(TPB) void matcher_cost_kernel(
    const float* __restrict__ logits,  // [NROWS, NCLS]
    const float* __restrict__ boxes,   // [NROWS, 4] cxcywh
    const int*   __restrict__ tids,    // [MTGT] (integer input -> int32 per harness)
    const float* __restrict__ tbox,    // [MTGT, 4] cxcywh
    float*       __restrict__ out)     // [NROWS, MTGT]
{
    __shared__ float s_cc[RPB * NCLS];   // focal class cost per (row, class)
    const int row0 = blockIdx.x * RPB;
    const int t = threadIdx.x;

    // --- Stage 1: per-row focal classification cost table (transcendentals
    //     done once per (row,class), NOT per pair) ---
    for (int i = t; i < RPB * NCLS; i += TPB) {
        const int r = i / NCLS;
        const int c = i - r * NCLS;
        const float x = logits[(size_t)(row0 + r) * NCLS + c];
        const float p = 1.0f / (1.0f + __expf(-x));          // sigmoid
        const float omp = 1.0f - p;
        // neg = (1-a)*p^2 * -log1p(-p+eps); pos = a*(1-p)^2 * -log(p+eps)
        const float neg = 0.75f * p * p * (-log1pf(-p + 1e-8f));
        const float pos = 0.25f * omp * omp * (-logf(p + 1e-8f));
        s_cc[i] = pos - neg;
    }
    __syncthreads();

    // --- Stage 2: pred boxes for the block's rows (uniform address ->
    //     compiler scalarizes to s_load; 8 float4 in registers) ---
    float4 pb[RPB];
    const float4* bx4 = reinterpret_cast<const float4*>(boxes);
#pragma unroll
    for (int r = 0; r < RPB; ++r) pb[r] = bx4[row0 + r];

    // --- Stage 3: pairwise costs. thread t owns columns m = t, t+320, ... ---
    const float4* tb4 = reinterpret_cast<const float4*>(tbox);
    for (int m = t; m < MTGT; m += TPB) {
        const float4 tb = tb4[m];          // coalesced 16B
        const int id = tids[m];            // coalesced 4B
        const float tx0 = tb.x - 0.5f * tb.z, tx1 = tb.x + 0.5f * tb.z;
        const float ty0 = tb.y - 0.5f * tb.w, ty1 = tb.y + 0.5f * tb.w;
        const float ta  = tb.z * tb.w;     // xyxy area == w*h
#pragma unroll
        for (int r = 0; r < RPB; ++r) {    // static indexing (no scratch)
            const float cc = s_cc[r * NCLS + id];   // LDS gather
            const float4 p = pb[r];
            // L1 on raw cxcywh
            const float l1 = fabsf(p.x - tb.x) + fabsf(p.y - tb.y)
                           + fabsf(p.z - tb.z) + fabsf(p.w - tb.w);
            // pred xyxy (loop-invariant wrt m; LICM hoists)
            const float px0 = p.x - 0.5f * p.z, px1 = p.x + 0.5f * p.z;
            const float py0 = p.y - 0.5f * p.w, py1 = p.y + 0.5f * p.w;
            const float pa  = p.z * p.w;
            // intersection
            const float iw = fminf(px1, tx1) - fmaxf(px0, tx0);
            const float ih = fminf(py1, ty1) - fmaxf(py0, ty0);
            const float inter = fmaxf(iw, 0.0f) * fmaxf(ih, 0.0f);
            const float uni = pa + ta - inter;
            const float iou = inter * __builtin_amdgcn_rcpf(uni);
            // enclosing box (always non-degenerate; clip not needed)
            const float ew = fmaxf(px1, tx1) - fminf(px0, tx0);
            const float eh = fmaxf(py1, ty1) - fminf(py0, ty0);
            const float ea = ew * eh;
            const float giou = iou - (ea - uni) * __builtin_amdgcn_rcpf(ea);
            // C = cost_bbox + cost_class + (-giou), all weights 1.0
            out[(size_t)(row0 + r) * MTGT + m] = l1 + cc - giou;
        }
    }
}

extern "C" void kernel_launch(void* const* d_in, const int* in_sizes, int n_in,
                              void* d_out, int out_size, void* d_ws, size_t ws_size,
                              hipStream_t stream) {
    const float* logits = (const float*)d_in[0];
    const float* boxes  = (const float*)d_in[1];
    const int*   tids   = (const int*)d_in[2];
    const float* tbox   = (const float*)d_in[3];
    float* out = (float*)d_out;

    dim3 grid(NROWS / RPB);   // 1800 blocks
    dim3 block(TPB);          // 320 threads = 5 waves
    hipLaunchKernelGGL(matcher_cost_kernel, grid, block, 0, stream,
                       logits, boxes, tids, tbox, out);
}